// Round 6
// baseline (957.119 us; speedup 1.0000x reference)
//
#include <hip/hip_runtime.h>

#define INF_F 3.402823466e+38f
typedef unsigned long long u64;
typedef __attribute__((ext_vector_type(2))) float f32x2;

__device__ __forceinline__ float f_add(float a, float b){ return __fadd_rn(a,b); }
__device__ __forceinline__ float f_sub(float a, float b){ return __fsub_rn(a,b); }
__device__ __forceinline__ float f_mul(float a, float b){ return __fmul_rn(a,b); }

// Packed fp32 (VOP3P) — same RN rounding as scalar, 2 elems/instr.
__device__ __forceinline__ f32x2 pk_add(f32x2 a, f32x2 b){ f32x2 d; asm("v_pk_add_f32 %0, %1, %2" : "=v"(d) : "v"(a), "v"(b)); return d; }
__device__ __forceinline__ f32x2 pk_mul(f32x2 a, f32x2 b){ f32x2 d; asm("v_pk_mul_f32 %0, %1, %2" : "=v"(d) : "v"(a), "v"(b)); return d; }
__device__ __forceinline__ f32x2 pk_fma(f32x2 a, f32x2 b, f32x2 c){ f32x2 d; asm("v_pk_fma_f32 %0, %1, %2, %3" : "=v"(d) : "v"(a), "v"(b), "v"(c)); return d; }

// DPP cross-lane (pure VALU). 0xB1=xor1, 0x4E=xor2, 0x141=xor4(eq), 0x140=xor8(eq),
// 0x142=row_bcast15 (row r+1 <- lane r*16+15), 0x143=row_bcast31 (rows 2,3 <- lane 31).
// OLD{LO,HI} = value seen by lanes outside row_mask / invalid source (identity elem).
template<int CTRL, int RM, unsigned OLDLO, unsigned OLDHI>
__device__ __forceinline__ double dpp_d(double x) {
    u64 u = (u64)__double_as_longlong(x);
    int lo = __builtin_amdgcn_update_dpp((int)OLDLO, (int)(unsigned)u,        CTRL, RM, 0xF, true);
    int hi = __builtin_amdgcn_update_dpp((int)OLDHI, (int)(unsigned)(u>>32), CTRL, RM, 0xF, true);
    return __longlong_as_double((long long)(((u64)(unsigned)hi << 32) | (unsigned)lo));
}
template<int CTRL>
__device__ __forceinline__ float dpp_f(float x) {
    int r = __builtin_amdgcn_update_dpp(0, __float_as_int(x), CTRL, 0xF, 0xF, true);
    return __int_as_float(r);
}
__device__ __forceinline__ float swz16_f(float x) {
    return __int_as_float(__builtin_amdgcn_ds_swizzle(__float_as_int(x), 0x401F));
}
__device__ __forceinline__ double readlane_d(double x, int l) {
    u64 u = (u64)__double_as_longlong(x);
    int lo = __builtin_amdgcn_readlane((int)(unsigned)u,        l);
    int hi = __builtin_amdgcn_readlane((int)(unsigned)(u>>32), l);
    return __longlong_as_double((long long)(((u64)(unsigned)hi << 32) | (unsigned)lo));
}
__device__ __forceinline__ float readlane_f(float x, int l) {
    return __int_as_float(__builtin_amdgcn_readlane(__float_as_int(x), l));
}
__device__ __forceinline__ double pack_key(float nd, unsigned low) {
    return __longlong_as_double((long long)(((u64)__float_as_uint(nd) << 32) | (u64)low));
}

// wave-64 max reduce of non-negative f64 keys -> result in lane 63 (OLD=0 identity)
__device__ __forceinline__ double wave_max_key(double k) {
    k = fmax(k, dpp_d<0xB1, 0xF, 0u, 0u>(k));
    k = fmax(k, dpp_d<0x4E, 0xF, 0u, 0u>(k));
    k = fmax(k, dpp_d<0x141,0xF, 0u, 0u>(k));
    k = fmax(k, dpp_d<0x140,0xF, 0u, 0u>(k));
    k = fmax(k, dpp_d<0x142,0xE, 0u, 0u>(k));   // row_bcast15 -> rows 1,2,3
    k = fmax(k, dpp_d<0x143,0xC, 0u, 0u>(k));   // row_bcast31 -> rows 2,3
    return readlane_d(k, 63);
}
// wave-64 min reduce of f64 keys -> lane 63 (OLD=+inf identity)
__device__ __forceinline__ double wave_min_key(double k) {
    k = fmin(k, dpp_d<0xB1, 0xF, 0u, 0x7FF00000u>(k));
    k = fmin(k, dpp_d<0x4E, 0xF, 0u, 0x7FF00000u>(k));
    k = fmin(k, dpp_d<0x141,0xF, 0u, 0x7FF00000u>(k));
    k = fmin(k, dpp_d<0x140,0xF, 0u, 0x7FF00000u>(k));
    k = fmin(k, dpp_d<0x142,0xE, 0u, 0x7FF00000u>(k));
    k = fmin(k, dpp_d<0x143,0xC, 0u, 0x7FF00000u>(k));
    return readlane_d(k, 63);
}

// ---------------------------------------------------------------------------
// Kernel 1: FPS. One 256-thread block per batch. ONE LDS round-trip per
// iteration: wave reduce is pure VALU (DPP + row_bcast); the winning wave's
// centroid COORDS are extracted from registers (uniform switch + readlane)
// and carried through the reduction slots, so the next iteration starts with
// the centroid already in registers. Key = (bits(nd)<<32)|(4095-n) as f64:
// fmax == (value, lowest-index) lexicographic == np.argmax.
// ---------------------------------------------------------------------------
__global__ __launch_bounds__(256, 1) void fps_kernel(
    const float* __restrict__ xyz, const int* __restrict__ farthest_init,
    float* __restrict__ out_new_xyz)
{
    const int b    = blockIdx.x;
    const int tid  = threadIdx.x;
    const int lane = tid & 63;
    const int wid  = tid >> 6;

    __shared__ float  sx[4096], sy[4096], sz[4096];
    __shared__ int    hist[1024];
    __shared__ double red[2][4];
    __shared__ float  redc[2][4][3];

    const float* xb = xyz + (size_t)b * 4096 * 3;
    for (int n = tid; n < 4096; n += 256) {
        sx[n] = xb[n*3+0]; sy[n] = xb[n*3+1]; sz[n] = xb[n*3+2];
    }
    __syncthreads();

    f32x2 px[8], py[8], pz[8], dist2[8];
    #pragma unroll
    for (int jp = 0; jp < 8; ++jp) {
        const int n0 = (2*jp) * 256 + tid, n1 = n0 + 256;
        px[jp] = (f32x2){sx[n0], sx[n1]};
        py[jp] = (f32x2){sy[n0], sy[n1]};
        pz[jp] = (f32x2){sz[n0], sz[n1]};
        dist2[jp] = (f32x2){1e10f, 1e10f};
    }
    const unsigned lowbase = 4095u - (unsigned)tid;

    int far = farthest_init[b];
    float cx = sx[far], cy = sy[far], cz = sz[far];   // only prologue LDS centroid read
    int p = 0;
    #pragma unroll 1
    for (int it = 0; it < 1024; ++it) {
        if (tid == 0) hist[it] = far;
        const f32x2 ncx = (f32x2){-cx, -cx};
        const f32x2 ncy = (f32x2){-cy, -cy};
        const f32x2 ncz = (f32x2){-cz, -cz};

        double a0 = -1.0, a1 = -1.0, a2 = -1.0, a3 = -1.0;  // 4 indep chains
        #pragma unroll
        for (int jp = 0; jp < 8; ++jp) {
            f32x2 dx = pk_add(px[jp], ncx);          // x + (-c) == x - c exactly
            f32x2 dy = pk_add(py[jp], ncy);
            f32x2 dz = pk_add(pz[jp], ncz);
            // exact reference order: (dx^2 + dy^2) + dz^2, no FMA
            f32x2 d2 = pk_add(pk_add(pk_mul(dx,dx), pk_mul(dy,dy)), pk_mul(dz,dz));
            float nd0 = fminf(dist2[jp][0], d2[0]); dist2[jp][0] = nd0;
            float nd1 = fminf(dist2[jp][1], d2[1]); dist2[jp][1] = nd1;
            double k0 = pack_key(nd0, lowbase - (unsigned)((2*jp)*256));
            double k1 = pack_key(nd1, lowbase - (unsigned)((2*jp+1)*256));
            if (jp & 1) { a2 = fmax(a2, k0); a3 = fmax(a3, k1); }
            else        { a0 = fmax(a0, k0); a1 = fmax(a1, k1); }
        }
        double wkey = wave_max_key(fmax(fmax(a0, a1), fmax(a2, a3)));

        // wave-uniform winner -> extract owner's coords from registers
        const unsigned wlow = (unsigned)((u64)__double_as_longlong(wkey) & 0xFFFFFFFFull);
        const int n_w   = 4095 - (int)wlow;
        const int jsel  = n_w >> 8;        // 0..15, wave-uniform
        const int olane = n_w & 63;        // owner lane (owner is in this wave)
        float sxv, syv, szv;
        switch (jsel) {
            case  0: sxv=px[0][0]; syv=py[0][0]; szv=pz[0][0]; break;
            case  1: sxv=px[0][1]; syv=py[0][1]; szv=pz[0][1]; break;
            case  2: sxv=px[1][0]; syv=py[1][0]; szv=pz[1][0]; break;
            case  3: sxv=px[1][1]; syv=py[1][1]; szv=pz[1][1]; break;
            case  4: sxv=px[2][0]; syv=py[2][0]; szv=pz[2][0]; break;
            case  5: sxv=px[2][1]; syv=py[2][1]; szv=pz[2][1]; break;
            case  6: sxv=px[3][0]; syv=py[3][0]; szv=pz[3][0]; break;
            case  7: sxv=px[3][1]; syv=py[3][1]; szv=pz[3][1]; break;
            case  8: sxv=px[4][0]; syv=py[4][0]; szv=pz[4][0]; break;
            case  9: sxv=px[4][1]; syv=py[4][1]; szv=pz[4][1]; break;
            case 10: sxv=px[5][0]; syv=py[5][0]; szv=pz[5][0]; break;
            case 11: sxv=px[5][1]; syv=py[5][1]; szv=pz[5][1]; break;
            case 12: sxv=px[6][0]; syv=py[6][0]; szv=pz[6][0]; break;
            case 13: sxv=px[6][1]; syv=py[6][1]; szv=pz[6][1]; break;
            case 14: sxv=px[7][0]; syv=py[7][0]; szv=pz[7][0]; break;
            default: sxv=px[7][1]; syv=py[7][1]; szv=pz[7][1]; break;
        }
        const float cwx = readlane_f(sxv, olane);
        const float cwy = readlane_f(syv, olane);
        const float cwz = readlane_f(szv, olane);
        if (lane == 0) {
            red[p][wid] = wkey;
            redc[p][wid][0] = cwx; redc[p][wid][1] = cwy; redc[p][wid][2] = cwz;
        }
        __syncthreads();
        // fold 4 slots; keys are distinct (disjoint index sets) so > is exact
        const double k0 = red[p][0], k1 = red[p][1], k2 = red[p][2], k3 = red[p][3];
        const bool s1 = k1 > k0;
        const bool s3 = k3 > k2;
        const double k01 = s1 ? k1 : k0;
        const double k23 = s3 ? k3 : k2;
        const bool sf = k23 > k01;
        const double g = sf ? k23 : k01;
        const int i01 = s1 ? 1 : 0, i23 = s3 ? 3 : 2;
        const int iw  = sf ? i23 : i01;
        cx = redc[p][iw][0]; cy = redc[p][iw][1]; cz = redc[p][iw][2];
        far = 4095 - (int)(unsigned)((u64)__double_as_longlong(g) & 0xFFFFFFFFull);
        p ^= 1;   // double-buffered slots: 1 barrier per iteration
    }
    __syncthreads();
    #pragma unroll
    for (int q = 0; q < 4; ++q) {
        int s  = q * 256 + tid;
        int id = hist[s];
        float* o = out_new_xyz + ((size_t)b * 1024 + s) * 3;
        o[0] = sx[id]; o[1] = sy[id]; o[2] = sz[id];
    }
}

// ---------------------------------------------------------------------------
// Kernel 2: kNN top-32. One wave per centroid (4 waves/block, no barriers).
// f64 keys (bits(d)<<32)|n, distinct -> min == (dist, lowest idx) == top_k.
// Per lane: 8 cached group-minima; per round rebuild only the winner's group.
// Wave reduce fully VALU (DPP + row_bcast, identity=+inf).
// ---------------------------------------------------------------------------
template<int G>
__device__ __forceinline__ double rebuild8(const double (&key)[64], double w) {
    const double DINF = __builtin_huge_val();
    double m = DINF;
    #pragma unroll
    for (int e = 0; e < 8; ++e) {
        double v = key[G*8+e];
        v = (v > w) ? v : DINF;
        m = fmin(m, v);
    }
    return m;
}

__global__ __launch_bounds__(256, 1) void knn_kernel(
    const float* __restrict__ xyz, const float* __restrict__ new_xyz,
    int* __restrict__ out_idx)
{
    const int tid  = threadIdx.x;
    const int lane = tid & 63;
    const int wid  = tid >> 6;
    const int blk  = blockIdx.x * 4 + wid;   // 0..8191 = b*1024 + s
    const int b    = blk >> 10;

    const float* xb = xyz + (size_t)b * 4096 * 3;
    const float* cp = new_xyz + (size_t)blk * 3;
    const float cx = cp[0], cy = cp[1], cz = cp[2];
    const float src2 = f_add(f_add(f_mul(cx,cx), f_mul(cy,cy)), f_mul(cz,cz));

    double key[64];
    #pragma unroll
    for (int j = 0; j < 64; ++j) {
        const int n = j * 64 + lane;
        const float* pt = xb + n * 3;
        float x = pt[0], y = pt[1], z = pt[2];
        float dst2 = f_add(f_add(f_mul(x,x), f_mul(y,y)), f_mul(z,z));
        float dot  = f_add(f_add(f_mul(cx,x), f_mul(cy,y)), f_mul(cz,z));
        float d = f_sub(f_add(src2, dst2), f_mul(2.0f, dot));   // exact reference form
        key[j] = __longlong_as_double((long long)(((u64)__float_as_uint(d) << 32) | (u64)(unsigned)n));
    }

    double gm[8];
    #pragma unroll
    for (int g = 0; g < 8; ++g) {
        double m = key[g*8];
        #pragma unroll
        for (int e = 1; e < 8; ++e) m = fmin(m, key[g*8+e]);
        gm[g] = m;
    }

    double w = -1.0;            // below every key (tiny-negative d keys > -1)
    int myidx = 0;
    #pragma unroll 1
    for (int t = 0; t < 32; ++t) {
        double lm = fmin(fmin(fmin(gm[0], gm[1]), fmin(gm[2], gm[3])),
                         fmin(fmin(gm[4], gm[5]), fmin(gm[6], gm[7])));
        double gmin = wave_min_key(lm);
        int n = (int)(unsigned)((u64)__double_as_longlong(gmin) & 0xFFFFFFFFull);
        if (lane == t) myidx = n;
        w = gmin;
        const int gs = __builtin_amdgcn_readfirstlane(n >> 9);  // group = (n>>6)>>3
        switch (gs) {
            case 0: gm[0] = rebuild8<0>(key, w); break;
            case 1: gm[1] = rebuild8<1>(key, w); break;
            case 2: gm[2] = rebuild8<2>(key, w); break;
            case 3: gm[3] = rebuild8<3>(key, w); break;
            case 4: gm[4] = rebuild8<4>(key, w); break;
            case 5: gm[5] = rebuild8<5>(key, w); break;
            case 6: gm[6] = rebuild8<6>(key, w); break;
            case 7: gm[7] = rebuild8<7>(key, w); break;
        }
    }
    if (lane < 32) out_idx[(size_t)blk * 32 + lane] = myidx;
}

// ---------------------------------------------------------------------------
// Kernel 3: 3-layer MLP + max-pool over K=32. thread = (centroid, k).
// Layers 2/3 via v_pk_fma_f32 (2 FMA/instr); maxpool via DPP/swizzle.
// ---------------------------------------------------------------------------
__global__ __launch_bounds__(256, 1) void mlp_kernel(
    const float* __restrict__ xyz, const float* __restrict__ points,
    const int* __restrict__ knn_idx,
    const float* __restrict__ w0, const float* __restrict__ b0,
    const float* __restrict__ w1, const float* __restrict__ b1,
    const float* __restrict__ w2, const float* __restrict__ b2,
    const float* __restrict__ new_xyz, float* __restrict__ out_np)
{
    const int tid = threadIdx.x;
    const int k   = tid & 31;
    const int gs  = blockIdx.x * 8 + (tid >> 5);   // 0..8191
    const int b   = gs >> 10;
    const int n   = knn_idx[(size_t)gs * 32 + k];

    const float cx = new_xyz[gs*3+0], cy = new_xyz[gs*3+1], cz = new_xyz[gs*3+2];
    const float* pxyz = xyz + ((size_t)b * 4096 + n) * 3;
    float h0[9];
    h0[0] = pxyz[0] - cx;
    h0[1] = pxyz[1] - cy;
    h0[2] = pxyz[2] - cz;
    const float* pp = points + ((size_t)b * 4096 + n) * 6;
    #pragma unroll
    for (int c = 0; c < 6; ++c) h0[3 + c] = pp[c];

    f32x2 h1p[32];
    #pragma unroll
    for (int o = 0; o < 64; o += 2) {
        float accA = b0[o], accB = b0[o+1];
        #pragma unroll
        for (int c = 0; c < 9; ++c) {
            accA = fmaf(h0[c], w0[o*9+c],     accA);
            accB = fmaf(h0[c], w0[(o+1)*9+c], accB);
        }
        h1p[o>>1] = (f32x2){fmaxf(accA, 0.0f), fmaxf(accB, 0.0f)};
    }

    const f32x2* w1v = (const f32x2*)w1;   // [64][32] pairs
    f32x2 h2p[32];
    #pragma unroll
    for (int o = 0; o < 64; o += 2) {
        f32x2 accA = (f32x2){b1[o],   0.0f};
        f32x2 accB = (f32x2){b1[o+1], 0.0f};
        #pragma unroll
        for (int i = 0; i < 32; ++i) {
            accA = pk_fma(h1p[i], w1v[o*32+i],     accA);
            accB = pk_fma(h1p[i], w1v[(o+1)*32+i], accB);
        }
        h2p[o>>1] = (f32x2){fmaxf(accA[0]+accA[1], 0.0f), fmaxf(accB[0]+accB[1], 0.0f)};
    }

    const f32x2* w2v = (const f32x2*)w2;   // [128][32] pairs
    float* outp = out_np + (size_t)gs * 128;
    for (int og = 0; og < 4; ++og) {
        float keep = 0.0f;
        for (int o2 = 0; o2 < 32; ++o2) {
            const int o = og * 32 + o2;
            f32x2 acc = (f32x2){b2[o], 0.0f};
            #pragma unroll
            for (int i = 0; i < 32; ++i) acc = pk_fma(h2p[i], w2v[o*32+i], acc);
            float m = fmaxf(acc[0] + acc[1], 0.0f);
            // max over the 32 k-lanes (never crosses the 32-lane half)
            m = fmaxf(m, dpp_f<0xB1>(m));
            m = fmaxf(m, dpp_f<0x4E>(m));
            m = fmaxf(m, dpp_f<0x141>(m));
            m = fmaxf(m, dpp_f<0x140>(m));
            m = fmaxf(m, swz16_f(m));
            keep = (k == o2) ? m : keep;
        }
        outp[og * 32 + k] = keep;
    }
}

// ---------------------------------------------------------------------------
// Fallback (ws too small): fused kNN+MLP (known-correct).
// ---------------------------------------------------------------------------
__global__ __launch_bounds__(256) void knn_mlp_kernel(
    const float* __restrict__ xyz, const float* __restrict__ points,
    const float* __restrict__ w0, const float* __restrict__ b0,
    const float* __restrict__ w1, const float* __restrict__ b1,
    const float* __restrict__ w2, const float* __restrict__ b2,
    const float* __restrict__ new_xyz, float* __restrict__ out_np)
{
    const int blk    = blockIdx.x;
    const int b      = blk >> 7;
    const int s_base = (blk & 127) * 8;
    const int tid    = threadIdx.x;
    const int lane   = tid & 63;
    const int wid    = tid >> 6;

    __shared__ float sx[4096], sy[4096], sz[4096];
    __shared__ float cent[8][3];
    __shared__ int   idxbuf[8][32];

    const float* xb = xyz + (size_t)b * 4096 * 3;
    for (int n = tid; n < 4096; n += 256) {
        sx[n] = xb[n*3+0]; sy[n] = xb[n*3+1]; sz[n] = xb[n*3+2];
    }
    if (tid < 24) ((float*)cent)[tid] = new_xyz[((size_t)b * 1024 + s_base) * 3 + tid];
    __syncthreads();

    for (int si = 0; si < 2; ++si) {
        const int sl = wid * 2 + si;
        const float cx = cent[sl][0], cy = cent[sl][1], cz = cent[sl][2];
        const float src2 = f_add(f_add(f_mul(cx,cx), f_mul(cy,cy)), f_mul(cz,cz));
        float d[64];
        #pragma unroll
        for (int j = 0; j < 64; ++j) {
            int n = j * 64 + lane;
            float x = sx[n], y = sy[n], z = sz[n];
            float dst2 = f_add(f_add(f_mul(x,x), f_mul(y,y)), f_mul(z,z));
            float dot  = f_add(f_add(f_mul(cx,x), f_mul(cy,y)), f_mul(cz,z));
            d[j] = f_sub(f_add(src2, dst2), f_mul(2.0f, dot));
        }
        int myg  = 0;
        int prev = -1;
        for (int t = 0; t < 32; ++t) {
            float bv = INF_F; int bi = 0x7fffffff;
            #pragma unroll
            for (int j = 0; j < 64; ++j) {
                int n = j * 64 + lane;
                if (n == prev) d[j] = INF_F;
                float v = d[j];
                if (v < bv) { bv = v; bi = n; }
            }
            #pragma unroll
            for (int m = 1; m < 64; m <<= 1) {
                float ov = __shfl_xor(bv, m);
                int   oi = __shfl_xor(bi, m);
                if (ov < bv || (ov == bv && oi < bi)) { bv = ov; bi = oi; }
            }
            if (lane == t) myg = bi;
            prev = bi;
        }
        if (lane < 32) idxbuf[sl][lane] = myg;
    }
    __syncthreads();

    const int k   = tid & 31;
    const int sl2 = tid >> 5;
    const int s   = s_base + sl2;
    const int n   = idxbuf[sl2][k];

    const float cx = cent[sl2][0], cy = cent[sl2][1], cz = cent[sl2][2];
    float h0[9];
    h0[0] = sx[n] - cx;
    h0[1] = sy[n] - cy;
    h0[2] = sz[n] - cz;
    const float* pp = points + ((size_t)b * 4096 + n) * 6;
    #pragma unroll
    for (int c = 0; c < 6; ++c) h0[3 + c] = pp[c];

    float h1[64];
    #pragma unroll
    for (int o = 0; o < 64; ++o) {
        float acc = b0[o];
        #pragma unroll
        for (int c = 0; c < 9; ++c) acc = fmaf(h0[c], w0[o*9+c], acc);
        h1[o] = fmaxf(acc, 0.0f);
    }
    float h2[64];
    #pragma unroll
    for (int o = 0; o < 64; ++o) {
        float acc = b1[o];
        #pragma unroll
        for (int c = 0; c < 64; ++c) acc = fmaf(h1[c], w1[o*64+c], acc);
        h2[o] = fmaxf(acc, 0.0f);
    }
    float* outp = out_np + ((size_t)b * 1024 + s) * 128;
    for (int og = 0; og < 4; ++og) {
        float keep = 0.0f;
        for (int o2 = 0; o2 < 32; ++o2) {
            const int o = og * 32 + o2;
            float acc = b2[o];
            #pragma unroll
            for (int c = 0; c < 64; ++c) acc = fmaf(h2[c], w2[o*64+c], acc);
            float m = fmaxf(acc, 0.0f);
            #pragma unroll
            for (int mm = 1; mm < 32; mm <<= 1)
                m = fmaxf(m, __shfl_xor(m, mm));
            keep = (k == o2) ? m : keep;
        }
        outp[og * 32 + k] = keep;
    }
}

extern "C" void kernel_launch(void* const* d_in, const int* in_sizes, int n_in,
                              void* d_out, int out_size, void* d_ws, size_t ws_size,
                              hipStream_t stream) {
    const float* xyz           = (const float*)d_in[0];
    const float* points        = (const float*)d_in[1];
    const int*   farthest_init = (const int*)  d_in[2];
    const float* w0 = (const float*)d_in[3];
    const float* b0 = (const float*)d_in[4];
    const float* w1 = (const float*)d_in[5];
    const float* b1 = (const float*)d_in[6];
    const float* w2 = (const float*)d_in[7];
    const float* b2 = (const float*)d_in[8];

    float* out        = (float*)d_out;
    float* new_xyz    = out;                 // [8,1024,3]
    float* new_points = out + 8 * 1024 * 3;  // [8,1024,128]

    fps_kernel<<<8, 256, 0, stream>>>(xyz, farthest_init, new_xyz);

    if (ws_size >= (size_t)(8192 * 32 * sizeof(int))) {
        int* knn_idx = (int*)d_ws;
        knn_kernel<<<2048, 256, 0, stream>>>(xyz, new_xyz, knn_idx);
        mlp_kernel<<<1024, 256, 0, stream>>>(xyz, points, knn_idx,
                                             w0, b0, w1, b1, w2, b2,
                                             new_xyz, new_points);
    } else {
        knn_mlp_kernel<<<1024, 256, 0, stream>>>(xyz, points, w0, b0, w1, b1, w2, b2,
                                                 new_xyz, new_points);
    }
}

// Round 7
// 781.046 us; speedup vs baseline: 1.2254x; 1.2254x over previous
//
#include <hip/hip_runtime.h>

#define INF_F 3.402823466e+38f
typedef unsigned long long u64;
typedef __attribute__((ext_vector_type(2))) float f32x2;

__device__ __forceinline__ float f_add(float a, float b){ return __fadd_rn(a,b); }
__device__ __forceinline__ float f_sub(float a, float b){ return __fsub_rn(a,b); }
__device__ __forceinline__ float f_mul(float a, float b){ return __fmul_rn(a,b); }

// Packed fp32 (VOP3P) — same RN rounding as scalar, 2 elems/instr.
__device__ __forceinline__ f32x2 pk_add(f32x2 a, f32x2 b){ f32x2 d; asm("v_pk_add_f32 %0, %1, %2" : "=v"(d) : "v"(a), "v"(b)); return d; }
__device__ __forceinline__ f32x2 pk_mul(f32x2 a, f32x2 b){ f32x2 d; asm("v_pk_mul_f32 %0, %1, %2" : "=v"(d) : "v"(a), "v"(b)); return d; }
__device__ __forceinline__ f32x2 pk_fma(f32x2 a, f32x2 b, f32x2 c){ f32x2 d; asm("v_pk_fma_f32 %0, %1, %2, %3" : "=v"(d) : "v"(a), "v"(b), "v"(c)); return d; }

// DPP cross-lane (pure VALU). 0xB1=xor1, 0x4E=xor2, 0x141=xor4, 0x140=xor8.
// All four patterns have valid sources for every lane -> OLD operand unused.
template<int CTRL>
__device__ __forceinline__ double dpp_d(double x) {
    u64 u = (u64)__double_as_longlong(x);
    int lo = __builtin_amdgcn_update_dpp(0, (int)(unsigned)u,        CTRL, 0xF, 0xF, true);
    int hi = __builtin_amdgcn_update_dpp(0, (int)(unsigned)(u>>32), CTRL, 0xF, 0xF, true);
    return __longlong_as_double((long long)(((u64)(unsigned)hi << 32) | (unsigned)lo));
}
template<int CTRL>
__device__ __forceinline__ float dpp_f(float x) {
    int r = __builtin_amdgcn_update_dpp(0, __float_as_int(x), CTRL, 0xF, 0xF, true);
    return __int_as_float(r);
}
__device__ __forceinline__ float swz16_f(float x) {
    return __int_as_float(__builtin_amdgcn_ds_swizzle(__float_as_int(x), 0x401F));
}
__device__ __forceinline__ double readlane_d(double x, int l) {
    u64 u = (u64)__double_as_longlong(x);
    int lo = __builtin_amdgcn_readlane((int)(unsigned)u,        l);
    int hi = __builtin_amdgcn_readlane((int)(unsigned)(u>>32), l);
    return __longlong_as_double((long long)(((u64)(unsigned)hi << 32) | (unsigned)lo));
}
__device__ __forceinline__ double pack_key(float nd, unsigned low) {
    return __longlong_as_double((long long)(((u64)__float_as_uint(nd) << 32) | (u64)low));
}

// wave-64 reduce: 4 xor-DPP stages (16-groups done), then readlane tree.
__device__ __forceinline__ double wave_max_key(double k) {
    k = fmax(k, dpp_d<0xB1>(k));
    k = fmax(k, dpp_d<0x4E>(k));
    k = fmax(k, dpp_d<0x141>(k));
    k = fmax(k, dpp_d<0x140>(k));
    double a = readlane_d(k, 0),  b = readlane_d(k, 16);
    double c = readlane_d(k, 32), d = readlane_d(k, 48);
    return fmax(fmax(a, b), fmax(c, d));
}
__device__ __forceinline__ double wave_min_key(double k) {
    k = fmin(k, dpp_d<0xB1>(k));
    k = fmin(k, dpp_d<0x4E>(k));
    k = fmin(k, dpp_d<0x141>(k));
    k = fmin(k, dpp_d<0x140>(k));
    double a = readlane_d(k, 0),  b = readlane_d(k, 16);
    double c = readlane_d(k, 32), d = readlane_d(k, 48);
    return fmin(fmin(a, b), fmin(c, d));
}

// ---------------------------------------------------------------------------
// Kernel 1: FPS. One 256-thread block per batch. Round-5 structure (known
// 565 us) minus the LDS-pipe ops on the serial chain: wave reduce is DPP +
// readlane tree (no ds_swizzle); centroid fetch is ONE ds_read_b128 from the
// interleaved float4 LDS array. Key = (bits(nd)<<32)|(4095-n) as f64:
// fmax == (value, lowest-index) lexicographic == np.argmax.
// ---------------------------------------------------------------------------
__global__ __launch_bounds__(256, 1) void fps_kernel(
    const float* __restrict__ xyz, const int* __restrict__ farthest_init,
    float* __restrict__ out_new_xyz)
{
    const int b    = blockIdx.x;
    const int tid  = threadIdx.x;
    const int lane = tid & 63;
    const int wid  = tid >> 6;

    __shared__ float4 sp[4096];
    __shared__ int    hist[1024];
    __shared__ double red[2][4];

    const float* xb = xyz + (size_t)b * 4096 * 3;
    for (int n = tid; n < 4096; n += 256)
        sp[n] = make_float4(xb[n*3+0], xb[n*3+1], xb[n*3+2], 0.0f);
    __syncthreads();

    f32x2 px[8], py[8], pz[8], dist2[8];
    #pragma unroll
    for (int jp = 0; jp < 8; ++jp) {
        const int n0 = (2*jp) * 256 + tid, n1 = n0 + 256;
        float4 a = sp[n0], c = sp[n1];
        px[jp] = (f32x2){a.x, c.x};
        py[jp] = (f32x2){a.y, c.y};
        pz[jp] = (f32x2){a.z, c.z};
        dist2[jp] = (f32x2){1e10f, 1e10f};
    }
    const unsigned lowbase = 4095u - (unsigned)tid;

    int far = farthest_init[b];
    float4 cen = sp[far];
    float cx = cen.x, cy = cen.y, cz = cen.z;
    int p = 0;
    #pragma unroll 1
    for (int it = 0; it < 1024; ++it) {
        if (tid == 0) hist[it] = far;
        const f32x2 ncx = (f32x2){-cx, -cx};
        const f32x2 ncy = (f32x2){-cy, -cy};
        const f32x2 ncz = (f32x2){-cz, -cz};

        double a0 = -1.0, a1 = -1.0, a2 = -1.0, a3 = -1.0;  // 4 indep chains
        #pragma unroll
        for (int jp = 0; jp < 8; ++jp) {
            f32x2 dx = pk_add(px[jp], ncx);          // x + (-c) == x - c exactly
            f32x2 dy = pk_add(py[jp], ncy);
            f32x2 dz = pk_add(pz[jp], ncz);
            // exact reference order: (dx^2 + dy^2) + dz^2, no FMA
            f32x2 d2 = pk_add(pk_add(pk_mul(dx,dx), pk_mul(dy,dy)), pk_mul(dz,dz));
            float nd0 = fminf(dist2[jp][0], d2[0]); dist2[jp][0] = nd0;
            float nd1 = fminf(dist2[jp][1], d2[1]); dist2[jp][1] = nd1;
            double k0 = pack_key(nd0, lowbase - (unsigned)((2*jp)*256));
            double k1 = pack_key(nd1, lowbase - (unsigned)((2*jp+1)*256));
            if (jp & 1) { a2 = fmax(a2, k0); a3 = fmax(a3, k1); }
            else        { a0 = fmax(a0, k0); a1 = fmax(a1, k1); }
        }
        double wkey = wave_max_key(fmax(fmax(a0, a1), fmax(a2, a3)));
        if (lane == 0) red[p][wid] = wkey;
        __syncthreads();
        const double g = fmax(fmax(red[p][0], red[p][1]),
                              fmax(red[p][2], red[p][3]));
        far = 4095 - (int)(unsigned)((u64)__double_as_longlong(g) & 0xFFFFFFFFull);
        float4 cc = sp[far];                  // single ds_read_b128
        cx = cc.x; cy = cc.y; cz = cc.z;
        p ^= 1;   // double-buffered slots: 1 barrier per iteration
    }
    __syncthreads();
    #pragma unroll
    for (int q = 0; q < 4; ++q) {
        int s  = q * 256 + tid;
        float4 cc = sp[hist[s]];
        float* o = out_new_xyz + ((size_t)b * 1024 + s) * 3;
        o[0] = cc.x; o[1] = cc.y; o[2] = cc.z;
    }
}

// ---------------------------------------------------------------------------
// Kernel 2: kNN top-32. One wave per centroid (4 waves/block, no barriers).
// f64 keys (bits(d)<<32)|n, distinct -> min == (dist, lowest idx) == top_k.
// Per lane: 8 cached group-minima; per round rebuild only the winner's group.
// Wave reduce: DPP + readlane tree (no LDS on the chain).
// ---------------------------------------------------------------------------
template<int G>
__device__ __forceinline__ double rebuild8(const double (&key)[64], double w) {
    const double DINF = __builtin_huge_val();
    double m = DINF;
    #pragma unroll
    for (int e = 0; e < 8; ++e) {
        double v = key[G*8+e];
        v = (v > w) ? v : DINF;
        m = fmin(m, v);
    }
    return m;
}

__global__ __launch_bounds__(256, 1) void knn_kernel(
    const float* __restrict__ xyz, const float* __restrict__ new_xyz,
    int* __restrict__ out_idx)
{
    const int tid  = threadIdx.x;
    const int lane = tid & 63;
    const int wid  = tid >> 6;
    const int blk  = blockIdx.x * 4 + wid;   // 0..8191 = b*1024 + s
    const int b    = blk >> 10;

    const float* xb = xyz + (size_t)b * 4096 * 3;
    const float* cp = new_xyz + (size_t)blk * 3;
    const float cx = cp[0], cy = cp[1], cz = cp[2];
    const float src2 = f_add(f_add(f_mul(cx,cx), f_mul(cy,cy)), f_mul(cz,cz));

    double key[64];
    #pragma unroll
    for (int j = 0; j < 64; ++j) {
        const int n = j * 64 + lane;
        const float* pt = xb + n * 3;
        float x = pt[0], y = pt[1], z = pt[2];
        float dst2 = f_add(f_add(f_mul(x,x), f_mul(y,y)), f_mul(z,z));
        float dot  = f_add(f_add(f_mul(cx,x), f_mul(cy,y)), f_mul(cz,z));
        float d = f_sub(f_add(src2, dst2), f_mul(2.0f, dot));   // exact reference form
        key[j] = __longlong_as_double((long long)(((u64)__float_as_uint(d) << 32) | (u64)(unsigned)n));
    }

    double gm[8];
    #pragma unroll
    for (int g = 0; g < 8; ++g) {
        double m = key[g*8];
        #pragma unroll
        for (int e = 1; e < 8; ++e) m = fmin(m, key[g*8+e]);
        gm[g] = m;
    }

    double w = -1.0;            // below every key (tiny-negative d keys > -1)
    int myidx = 0;
    #pragma unroll 1
    for (int t = 0; t < 32; ++t) {
        double lm = fmin(fmin(fmin(gm[0], gm[1]), fmin(gm[2], gm[3])),
                         fmin(fmin(gm[4], gm[5]), fmin(gm[6], gm[7])));
        double gmin = wave_min_key(lm);
        int n = (int)(unsigned)((u64)__double_as_longlong(gmin) & 0xFFFFFFFFull);
        if (lane == t) myidx = n;
        w = gmin;
        const int gs = __builtin_amdgcn_readfirstlane(n >> 9);  // group = (n>>6)>>3
        switch (gs) {
            case 0: gm[0] = rebuild8<0>(key, w); break;
            case 1: gm[1] = rebuild8<1>(key, w); break;
            case 2: gm[2] = rebuild8<2>(key, w); break;
            case 3: gm[3] = rebuild8<3>(key, w); break;
            case 4: gm[4] = rebuild8<4>(key, w); break;
            case 5: gm[5] = rebuild8<5>(key, w); break;
            case 6: gm[6] = rebuild8<6>(key, w); break;
            case 7: gm[7] = rebuild8<7>(key, w); break;
        }
    }
    if (lane < 32) out_idx[(size_t)blk * 32 + lane] = myidx;
}

// ---------------------------------------------------------------------------
// Kernel 3: 3-layer MLP + max-pool over K=32. thread = (centroid, k).
// Layers 2/3 via v_pk_fma_f32; maxpool via DPP/swizzle.
// ---------------------------------------------------------------------------
__global__ __launch_bounds__(256, 1) void mlp_kernel(
    const float* __restrict__ xyz, const float* __restrict__ points,
    const int* __restrict__ knn_idx,
    const float* __restrict__ w0, const float* __restrict__ b0,
    const float* __restrict__ w1, const float* __restrict__ b1,
    const float* __restrict__ w2, const float* __restrict__ b2,
    const float* __restrict__ new_xyz, float* __restrict__ out_np)
{
    const int tid = threadIdx.x;
    const int k   = tid & 31;
    const int gs  = blockIdx.x * 8 + (tid >> 5);   // 0..8191
    const int b   = gs >> 10;
    const int n   = knn_idx[(size_t)gs * 32 + k];

    const float cx = new_xyz[gs*3+0], cy = new_xyz[gs*3+1], cz = new_xyz[gs*3+2];
    const float* pxyz = xyz + ((size_t)b * 4096 + n) * 3;
    float h0[9];
    h0[0] = pxyz[0] - cx;
    h0[1] = pxyz[1] - cy;
    h0[2] = pxyz[2] - cz;
    const float* pp = points + ((size_t)b * 4096 + n) * 6;
    #pragma unroll
    for (int c = 0; c < 6; ++c) h0[3 + c] = pp[c];

    f32x2 h1p[32];
    #pragma unroll
    for (int o = 0; o < 64; o += 2) {
        float accA = b0[o], accB = b0[o+1];
        #pragma unroll
        for (int c = 0; c < 9; ++c) {
            accA = fmaf(h0[c], w0[o*9+c],     accA);
            accB = fmaf(h0[c], w0[(o+1)*9+c], accB);
        }
        h1p[o>>1] = (f32x2){fmaxf(accA, 0.0f), fmaxf(accB, 0.0f)};
    }

    const f32x2* w1v = (const f32x2*)w1;   // [64][32] pairs
    f32x2 h2p[32];
    #pragma unroll
    for (int o = 0; o < 64; o += 2) {
        f32x2 accA = (f32x2){b1[o],   0.0f};
        f32x2 accB = (f32x2){b1[o+1], 0.0f};
        #pragma unroll
        for (int i = 0; i < 32; ++i) {
            accA = pk_fma(h1p[i], w1v[o*32+i],     accA);
            accB = pk_fma(h1p[i], w1v[(o+1)*32+i], accB);
        }
        h2p[o>>1] = (f32x2){fmaxf(accA[0]+accA[1], 0.0f), fmaxf(accB[0]+accB[1], 0.0f)};
    }

    const f32x2* w2v = (const f32x2*)w2;   // [128][32] pairs
    float* outp = out_np + (size_t)gs * 128;
    for (int og = 0; og < 4; ++og) {
        float keep = 0.0f;
        for (int o2 = 0; o2 < 32; ++o2) {
            const int o = og * 32 + o2;
            f32x2 acc = (f32x2){b2[o], 0.0f};
            #pragma unroll
            for (int i = 0; i < 32; ++i) acc = pk_fma(h2p[i], w2v[o*32+i], acc);
            float m = fmaxf(acc[0] + acc[1], 0.0f);
            // max over the 32 k-lanes (never crosses the 32-lane half)
            m = fmaxf(m, dpp_f<0xB1>(m));
            m = fmaxf(m, dpp_f<0x4E>(m));
            m = fmaxf(m, dpp_f<0x141>(m));
            m = fmaxf(m, dpp_f<0x140>(m));
            m = fmaxf(m, swz16_f(m));
            keep = (k == o2) ? m : keep;
        }
        outp[og * 32 + k] = keep;
    }
}

// ---------------------------------------------------------------------------
// Fallback (ws too small): fused kNN+MLP (known-correct).
// ---------------------------------------------------------------------------
__global__ __launch_bounds__(256) void knn_mlp_kernel(
    const float* __restrict__ xyz, const float* __restrict__ points,
    const float* __restrict__ w0, const float* __restrict__ b0,
    const float* __restrict__ w1, const float* __restrict__ b1,
    const float* __restrict__ w2, const float* __restrict__ b2,
    const float* __restrict__ new_xyz, float* __restrict__ out_np)
{
    const int blk    = blockIdx.x;
    const int b      = blk >> 7;
    const int s_base = (blk & 127) * 8;
    const int tid    = threadIdx.x;
    const int lane   = tid & 63;
    const int wid    = tid >> 6;

    __shared__ float sx[4096], sy[4096], sz[4096];
    __shared__ float cent[8][3];
    __shared__ int   idxbuf[8][32];

    const float* xb = xyz + (size_t)b * 4096 * 3;
    for (int n = tid; n < 4096; n += 256) {
        sx[n] = xb[n*3+0]; sy[n] = xb[n*3+1]; sz[n] = xb[n*3+2];
    }
    if (tid < 24) ((float*)cent)[tid] = new_xyz[((size_t)b * 1024 + s_base) * 3 + tid];
    __syncthreads();

    for (int si = 0; si < 2; ++si) {
        const int sl = wid * 2 + si;
        const float cx = cent[sl][0], cy = cent[sl][1], cz = cent[sl][2];
        const float src2 = f_add(f_add(f_mul(cx,cx), f_mul(cy,cy)), f_mul(cz,cz));
        float d[64];
        #pragma unroll
        for (int j = 0; j < 64; ++j) {
            int n = j * 64 + lane;
            float x = sx[n], y = sy[n], z = sz[n];
            float dst2 = f_add(f_add(f_mul(x,x), f_mul(y,y)), f_mul(z,z));
            float dot  = f_add(f_add(f_mul(cx,x), f_mul(cy,y)), f_mul(cz,z));
            d[j] = f_sub(f_add(src2, dst2), f_mul(2.0f, dot));
        }
        int myg  = 0;
        int prev = -1;
        for (int t = 0; t < 32; ++t) {
            float bv = INF_F; int bi = 0x7fffffff;
            #pragma unroll
            for (int j = 0; j < 64; ++j) {
                int n = j * 64 + lane;
                if (n == prev) d[j] = INF_F;
                float v = d[j];
                if (v < bv) { bv = v; bi = n; }
            }
            #pragma unroll
            for (int m = 1; m < 64; m <<= 1) {
                float ov = __shfl_xor(bv, m);
                int   oi = __shfl_xor(bi, m);
                if (ov < bv || (ov == bv && oi < bi)) { bv = ov; bi = oi; }
            }
            if (lane == t) myg = bi;
            prev = bi;
        }
        if (lane < 32) idxbuf[sl][lane] = myg;
    }
    __syncthreads();

    const int k   = tid & 31;
    const int sl2 = tid >> 5;
    const int s   = s_base + sl2;
    const int n   = idxbuf[sl2][k];

    const float cx = cent[sl2][0], cy = cent[sl2][1], cz = cent[sl2][2];
    float h0[9];
    h0[0] = sx[n] - cx;
    h0[1] = sy[n] - cy;
    h0[2] = sz[n] - cz;
    const float* pp = points + ((size_t)b * 4096 + n) * 6;
    #pragma unroll
    for (int c = 0; c < 6; ++c) h0[3 + c] = pp[c];

    float h1[64];
    #pragma unroll
    for (int o = 0; o < 64; ++o) {
        float acc = b0[o];
        #pragma unroll
        for (int c = 0; c < 9; ++c) acc = fmaf(h0[c], w0[o*9+c], acc);
        h1[o] = fmaxf(acc, 0.0f);
    }
    float h2[64];
    #pragma unroll
    for (int o = 0; o < 64; ++o) {
        float acc = b1[o];
        #pragma unroll
        for (int c = 0; c < 64; ++c) acc = fmaf(h1[c], w1[o*64+c], acc);
        h2[o] = fmaxf(acc, 0.0f);
    }
    float* outp = out_np + ((size_t)b * 1024 + s) * 128;
    for (int og = 0; og < 4; ++og) {
        float keep = 0.0f;
        for (int o2 = 0; o2 < 32; ++o2) {
            const int o = og * 32 + o2;
            float acc = b2[o];
            #pragma unroll
            for (int c = 0; c < 64; ++c) acc = fmaf(h2[c], w2[o*64+c], acc);
            float m = fmaxf(acc, 0.0f);
            #pragma unroll
            for (int mm = 1; mm < 32; mm <<= 1)
                m = fmaxf(m, __shfl_xor(m, mm));
            keep = (k == o2) ? m : keep;
        }
        outp[og * 32 + k] = keep;
    }
}

extern "C" void kernel_launch(void* const* d_in, const int* in_sizes, int n_in,
                              void* d_out, int out_size, void* d_ws, size_t ws_size,
                              hipStream_t stream) {
    const float* xyz           = (const float*)d_in[0];
    const float* points        = (const float*)d_in[1];
    const int*   farthest_init = (const int*)  d_in[2];
    const float* w0 = (const float*)d_in[3];
    const float* b0 = (const float*)d_in[4];
    const float* w1 = (const float*)d_in[5];
    const float* b1 = (const float*)d_in[6];
    const float* w2 = (const float*)d_in[7];
    const float* b2 = (const float*)d_in[8];

    float* out        = (float*)d_out;
    float* new_xyz    = out;                 // [8,1024,3]
    float* new_points = out + 8 * 1024 * 3;  // [8,1024,128]

    fps_kernel<<<8, 256, 0, stream>>>(xyz, farthest_init, new_xyz);

    if (ws_size >= (size_t)(8192 * 32 * sizeof(int))) {
        int* knn_idx = (int*)d_ws;
        knn_kernel<<<2048, 256, 0, stream>>>(xyz, new_xyz, knn_idx);
        mlp_kernel<<<1024, 256, 0, stream>>>(xyz, points, knn_idx,
                                             w0, b0, w1, b1, w2, b2,
                                             new_xyz, new_points);
    } else {
        knn_mlp_kernel<<<1024, 256, 0, stream>>>(xyz, points, w0, b0, w1, b1, w2, b2,
                                                 new_xyz, new_points);
    }
}